// Round 2
// baseline (433.274 us; speedup 1.0000x reference)
//
#include <hip/hip_runtime.h>

// Elementwise hard clip: out = clamp(x, -0.5, 0.5), fp32.
// N = 32*2*1048576 = 67108864 elements. Memory-bound:
// 537 MB kernel traffic -> ~85-100 us at ~6.3 TB/s achievable HBM BW.
// Grid-stride over out_size so every d_out element is written on every call.

__global__ __launch_bounds__(256) void clip_kernel(const float* __restrict__ x,
                                                   float* __restrict__ out,
                                                   long long n) {
    const float lo = -0.5f, hi = 0.5f;
    long long n4 = n >> 2;  // number of whole float4 groups
    long long stride = (long long)gridDim.x * blockDim.x;
    long long tid = (long long)blockIdx.x * blockDim.x + threadIdx.x;

    const float4* __restrict__ x4 = (const float4*)x;
    float4* __restrict__ o4 = (float4*)out;

    for (long long i = tid; i < n4; i += stride) {
        float4 v = x4[i];
        v.x = fminf(fmaxf(v.x, lo), hi);
        v.y = fminf(fmaxf(v.y, lo), hi);
        v.z = fminf(fmaxf(v.z, lo), hi);
        v.w = fminf(fmaxf(v.w, lo), hi);
        o4[i] = v;
    }

    // Scalar tail (n not divisible by 4) — no-op for this problem but cheap.
    for (long long i = (n4 << 2) + tid; i < n; i += stride) {
        out[i] = fminf(fmaxf(x[i], lo), hi);
    }
}

extern "C" void kernel_launch(void* const* d_in, const int* in_sizes, int n_in,
                              void* d_out, int out_size, void* d_ws, size_t ws_size,
                              hipStream_t stream) {
    const float* x = (const float*)d_in[0];
    float* out = (float*)d_out;
    long long n = (long long)out_size;  // 67108864
    int block = 256;
    int grid = 2048;  // 256 CUs x 8 workgroups: persistent-style streaming grid
    clip_kernel<<<grid, block, 0, stream>>>(x, out, n);
}